// Round 7
// baseline (245.211 us; speedup 1.0000x reference)
//
#include <hip/hip_runtime.h>
#include <math.h>

#define BB 8
#define SS 2048
#define DD 1024
#define MM 4096
#define dd 256
#define GRID 512
#define NCHK 128     // 16-row x chunks

// ---- ws layout (floats). First 64 floats = barrier state (memset each call).
#define OFF_PART  64
#define OFF_Q     (OFF_PART + BB*NCHK*DD)        // 64 + 1048576
#define OFF_WV    (OFF_Q + 2048)
#define OFF_GATE  (OFF_WV + 2048)
#define OFF_COMBO (OFF_GATE + 8)
#define OFF_SUMP  (OFF_COMBO + 8)                // 1024: [which*512 + b*64 + mc]
#define OFF_SC    (OFF_SUMP + 1024)              // 32768: write-side exp scores [b][m]
#define OFF_PRET  (OFF_SC + 32768)               // 131072: [(b*64+mc)*256 + j]
#define OFF_ROUT  (OFF_PRET + 131072)            // 8192

__device__ __forceinline__ void gbar(int* cnt, int target) {
    __syncthreads();
    if (threadIdx.x == 0) {
        __threadfence();   // release: agent-scope wb of this block's stores
        __hip_atomic_fetch_add(cnt, 1, __ATOMIC_RELAXED, __HIP_MEMORY_SCOPE_AGENT);
        while (__hip_atomic_load(cnt, __ATOMIC_RELAXED, __HIP_MEMORY_SCOPE_AGENT) < target)
            __builtin_amdgcn_s_sleep(8);
        __threadfence();   // acquire: invalidate stale L1/L2 before reads
    }
    __syncthreads();
}

__global__ __launch_bounds__(256, 4)
void mega(const float* __restrict__ x, const float* __restrict__ memory,
          const float* __restrict__ Wq, const float* __restrict__ bq,
          const float* __restrict__ Wv, const float* __restrict__ bv,
          const float* __restrict__ Wo, const float* __restrict__ bo,
          const float* __restrict__ Wg, const float* __restrict__ bg,
          float* __restrict__ ws, float* __restrict__ out) {
    __shared__ float4 xs4[256];
    __shared__ float red[256];
    __shared__ float esc[64];
    __shared__ float ret[256];
    __shared__ float ssum;
    const int blk = blockIdx.x;
    const int t = threadIdx.x;
    int* bar = (int*)ws;
    float4* PART4 = (float4*)(ws + OFF_PART);

    // ---- P1: x partial column sums (1024 units of 16 rows) ----
    for (int u = blk; u < BB*NCHK; u += GRID) {
        int b = u >> 7, chunk = u & 127;
        const float4* x4 = (const float4*)(x + ((size_t)b*SS + (size_t)chunk*16)*DD);
        float4 a = make_float4(0.f,0.f,0.f,0.f);
        #pragma unroll
        for (int s = 0; s < 16; ++s) {
            float4 v = x4[s*256 + t];
            a.x += v.x; a.y += v.y; a.z += v.z; a.w += v.w;
        }
        PART4[(size_t)u*256 + t] = a;
    }
    gbar(bar, GRID);

    // ---- P3: projections (blocks 0..127) + gate (blocks 128..135) ----
    if (blk < 128) {
        int which = blk >> 6;
        int b = (blk >> 3) & 7;
        int cgp = blk & 7;                 // 32-col group
        const float4* p4 = PART4 + (size_t)b*NCHK*256;
        float4 a = make_float4(0.f,0.f,0.f,0.f);
        #pragma unroll 8
        for (int c = 0; c < NCHK; ++c) {
            float4 v = p4[(size_t)c*256 + t];
            a.x += v.x; a.y += v.y; a.z += v.z; a.w += v.w;
        }
        xs4[t] = make_float4(a.x*(1.f/SS), a.y*(1.f/SS), a.z*(1.f/SS), a.w*(1.f/SS));
        __syncthreads();
        const float* xs = (const float*)xs4;
        const float* W = which ? Wv : Wq;
        int kg = t >> 5;                   // 8 k-groups of 128
        int c = cgp*32 + (t & 31);
        float acc = 0.f;
        #pragma unroll 8
        for (int kk = 0; kk < 128; ++kk) {
            int k = kg*128 + kk;
            acc += xs[k] * W[(size_t)k*dd + c];
        }
        red[t] = acc;
        __syncthreads();
        if (t < 32) {
            float o = 0.f;
            #pragma unroll
            for (int g = 0; g < 8; ++g) o += red[g*32 + t];
            int cc = cgp*32 + t;
            o += which ? bv[cc] : bq[cc];
            ws[(which ? OFF_WV : OFF_Q) + b*dd + cc] = o;
        }
    } else if (blk < 136) {
        int b = blk - 128;
        const float4* p4 = PART4 + (size_t)b*NCHK*256;
        float4 a = make_float4(0.f,0.f,0.f,0.f);
        #pragma unroll 8
        for (int c = 0; c < NCHK; ++c) {
            float4 v = p4[(size_t)c*256 + t];
            a.x += v.x; a.y += v.y; a.z += v.z; a.w += v.w;
        }
        float4 wg = ((const float4*)Wg)[t];
        red[t] = a.x*wg.x + a.y*wg.y + a.z*wg.z + a.w*wg.w;
        __syncthreads();
        for (int s2 = 128; s2 > 0; s2 >>= 1) {
            if (t < s2) red[t] += red[t + s2];
            __syncthreads();
        }
        if (t == 0)
            ws[OFF_GATE + b] = 1.f / (1.f + __expf(-(red[0]*(1.f/SS) + bg[0])));
    }
    gbar(bar, 2*GRID);

    // ---- P4: scores -> exp, row-sum partials, retrieval partials (1024 units) ----
    {
        int wave = t >> 6, lane = t & 63;
        for (int u = blk; u < 1024; u += GRID) {
            int which = u >> 9;
            int b = (u >> 6) & 7;
            int mc = u & 63;
            const float* tile = ((which == 0) ? memory : memory + (size_t)b*MM*dd)
                                + (size_t)mc*64*dd;
            const float4 qv = ((const float4*)(ws + OFF_Q + b*dd))[lane];
            #pragma unroll 4
            for (int i = 0; i < 16; ++i) {
                int r = i*4 + wave;
                float4 av = ((const float4*)(tile + (size_t)r*dd))[lane];
                float p = av.x*qv.x + av.y*qv.y + av.z*qv.z + av.w*qv.w;
                #pragma unroll
                for (int off = 32; off > 0; off >>= 1) p += __shfl_xor(p, off);
                if (lane == 0) esc[r] = __expf(p);
            }
            __syncthreads();
            if (t < 64) {
                float v = esc[t];
                #pragma unroll
                for (int off = 32; off > 0; off >>= 1) v += __shfl_xor(v, off);
                if (t == 0) ws[OFF_SUMP + which*512 + b*64 + mc] = v;
            }
            if (which == 0) {
                float acc = 0.f;
                #pragma unroll 8
                for (int i = 0; i < 64; ++i) acc += esc[i] * tile[(size_t)i*dd + t];
                ws[OFF_PRET + (size_t)(b*64 + mc)*dd + t] = acc;
            } else if (t < 64) {
                ws[OFF_SC + (size_t)b*MM + mc*64 + t] = esc[t];
            }
            __syncthreads();   // esc WAR before next unit
        }
    }
    gbar(bar, 3*GRID);

    // ---- P5: PRET reduce + normalize + Wo matvec + combo (128 units) ----
    if (blk < 128) {
        int cb = blk & 15;
        int b = blk >> 4;
        if (t < 64) {
            float v = ws[OFF_SUMP + b*64 + t];
            #pragma unroll
            for (int off = 32; off > 0; off >>= 1) v += __shfl_xor(v, off);
            if (t == 0) ssum = v;
        } else if (t < 128 && cb == 0) {
            float v = ws[OFF_SUMP + 512 + b*64 + (t - 64)];
            #pragma unroll
            for (int off = 32; off > 0; off >>= 1) v += __shfl_xor(v, off);
            if (t == 64) ws[OFF_COMBO + b] = 0.05f * ws[OFF_GATE + b] / v;
        }
        float acc0 = 0.f;
        #pragma unroll 8
        for (int mc = 0; mc < 64; ++mc)
            acc0 += ws[OFF_PRET + (size_t)(b*64 + mc)*dd + t];
        __syncthreads();
        ret[t] = acc0 / ssum;
        __syncthreads();
        int c = t & 63, jr = t >> 6;
        float acc = 0.f;
        #pragma unroll 8
        for (int jj = 0; jj < 64; ++jj) {
            int j = jr*64 + jj;
            acc += ret[j] * Wo[(size_t)j*DD + cb*64 + c];
        }
        red[t] = acc;
        __syncthreads();
        if (t < 64) {
            ws[OFF_ROUT + (size_t)b*DD + cb*64 + t] =
                red[t] + red[t+64] + red[t+128] + red[t+192] + bo[cb*64 + t];
        }
    }
    gbar(bar, 4*GRID);

    // ---- P6: fused elementwise outputs ----
    {
        const int NA = BB*SS*DD/4;       // 4194304
        const int NT = NA + BB*MM*dd/4;  // 6291456
        const float4* x4 = (const float4*)x;
        const float4* m4 = (const float4*)memory;
        const float4* r4 = (const float4*)(ws + OFF_ROUT);
        const float4* w4 = (const float4*)(ws + OFF_WV);
        float4* o4 = (float4*)out;
        const int stride = GRID*256;
        for (int i = blk*256 + t; i < NT; i += stride) {
            if (i < NA) {
                int b = i >> 19;
                int c = i & 255;
                float4 xv = x4[i];
                float4 rv = r4[(b << 8) + c];
                o4[i] = make_float4(xv.x+rv.x, xv.y+rv.y, xv.z+rv.z, xv.w+rv.w);
            } else {
                int j = i - NA;
                int b = j >> 18;
                int m = (j >> 6) & (MM-1);
                int d4 = j & 63;
                float coeff = ws[OFF_COMBO + b] * ws[OFF_SC + (size_t)b*MM + m];
                float4 wv = w4[(b << 6) + d4];
                float4 mv = m4[j];
                o4[i] = make_float4(0.95f*mv.x + coeff*wv.x,
                                    0.95f*mv.y + coeff*wv.y,
                                    0.95f*mv.z + coeff*wv.z,
                                    0.95f*mv.w + coeff*wv.w);
            }
        }
    }
}

extern "C" void kernel_launch(void* const* d_in, const int* in_sizes, int n_in,
                              void* d_out, int out_size, void* d_ws, size_t ws_size,
                              hipStream_t stream) {
    const float* x      = (const float*)d_in[0];
    const float* memory = (const float*)d_in[1];
    const float* Wq     = (const float*)d_in[2];
    const float* bq     = (const float*)d_in[3];
    const float* Wv     = (const float*)d_in[4];
    const float* bv     = (const float*)d_in[5];
    const float* Wo     = (const float*)d_in[6];
    const float* bo     = (const float*)d_in[7];
    const float* Wg     = (const float*)d_in[8];
    const float* bg     = (const float*)d_in[9];
    float* out = (float*)d_out;
    float* ws  = (float*)d_ws;

    hipMemsetAsync(ws, 0, 256, stream);   // zero barrier counters (capture-safe)
    mega<<<GRID, 256, 0, stream>>>(x, memory, Wq, bq, Wv, bv, Wo, bo, Wg, bg, ws, out);
}

// Round 9
// 139.644 us; speedup vs baseline: 1.7560x; 1.7560x over previous
//
#include <hip/hip_runtime.h>
#include <math.h>

#define BB 8
#define SS 2048
#define DD 1024
#define MM 4096
#define dd 256
#define NCHK 128     // 16-row x chunks

typedef float f4 __attribute__((ext_vector_type(4)));

// ---- ws layout (floats). ints ws[0..7] = per-b last-block counters (zeroed by k23).
#define OFF_PART  64                              // [b*128+chunk][1024] = 1048576
#define OFF_Q     (OFF_PART + BB*NCHK*DD)         // 2048
#define OFF_WV    (OFF_Q + 2048)                  // 2048
#define OFF_GATE  (OFF_WV + 2048)                 // 8
#define OFF_COMBO (OFF_GATE + 8)                  // 8
#define OFF_SUMP  (OFF_COMBO + 8)                 // 1024: [which*512 + b*64 + mc]
#define OFF_SC    (OFF_SUMP + 1024)               // 32768: exp write-scores [b][m]
#define OFF_PRET  (OFF_SC + 32768)                // 131072: [(b*64+mc)*256 + j]
#define OFF_ROUT  (OFF_PRET + 131072)             // 8192

// K1: x partial column sums. grid = B*NCHK = 1024, block 256, f4/thread.
__global__ void k1(const float* __restrict__ x, float* __restrict__ ws) {
    int blk = blockIdx.x;
    int chunk = blk & 127;
    int b = blk >> 7;
    int t = threadIdx.x;
    const f4* x4 = (const f4*)(x + ((size_t)b*SS + (size_t)chunk*16)*DD);
    f4 a = (f4)(0.f);
    #pragma unroll
    for (int s = 0; s < 16; ++s)
        a += __builtin_nontemporal_load(&x4[s*256 + t]);
    ((f4*)(ws + OFF_PART))[(size_t)blk*256 + t] = a;
}

// K23: fused projections + gate + counter zeroing. grid = 72 blocks, block 512.
__global__ void k23(const float* __restrict__ Wq, const float* __restrict__ bq,
                    const float* __restrict__ Wv, const float* __restrict__ bv,
                    const float* __restrict__ Wg, const float* __restrict__ bg,
                    float* __restrict__ ws) {
    __shared__ f4 xsA[256];
    __shared__ f4 xsB[256];
    __shared__ float red[512];
    int blk = blockIdx.x;
    int t = threadIdx.x;
    const f4* p4 = (const f4*)(ws + OFF_PART);
    if (blk == 71 && t < 8) ((int*)ws)[t] = 0;   // zero last-block counters for k45f
    if (blk < 64) {
        int cs = blk & 3;
        int wb = blk >> 2;
        int b = wb & 7;
        int which = wb >> 3;
        int col4 = t & 255;
        int half = t >> 8;
        f4 a = (f4)(0.f);
        #pragma unroll 8
        for (int c = 0; c < 64; ++c)
            a += p4[(size_t)(b*NCHK + half*64 + c)*256 + col4];
        if (half == 0) xsA[col4] = a; else xsB[col4] = a;
        __syncthreads();
        if (t < 256) xsA[t] = (xsA[t] + xsB[t]) * (1.f/SS);
        __syncthreads();
        const float* xs = (const float*)xsA;
        const float* W = which ? Wv : Wq;
        int kg = t >> 6;
        int c0 = cs*64 + (t & 63);
        float acc = 0.f;
        #pragma unroll 8
        for (int kk = 0; kk < 128; ++kk) {
            int k = kg*128 + kk;
            acc += xs[k] * W[(size_t)k*dd + c0];
        }
        red[t] = acc;
        __syncthreads();
        if (t < 64) {
            int c = cs*64 + t;
            float o = red[t] + red[t+64] + red[t+128] + red[t+192]
                    + red[t+256] + red[t+320] + red[t+384] + red[t+448];
            o += which ? bv[c] : bq[c];
            ws[(which ? OFF_WV : OFF_Q) + b*dd + c] = o;
        }
    } else {
        int b = blk - 64;
        const float* base = ws + OFF_PART + (size_t)(b*NCHK)*DD;
        float wg0 = Wg[t], wg1 = Wg[t + 512];
        float acc = 0.f;
        #pragma unroll 8
        for (int c = 0; c < NCHK; ++c) {
            const float* p = base + (size_t)c*DD;
            acc += p[t]*wg0 + p[t+512]*wg1;
        }
        red[t] = acc; __syncthreads();
        for (int s2 = 256; s2 > 0; s2 >>= 1) {
            if (t < s2) red[t] += red[t + s2];
            __syncthreads();
        }
        if (t == 0)
            ws[OFF_GATE + b] = 1.f / (1.f + __expf(-(red[0]*(1.f/SS) + bg[0])));
    }
}

// K45F: scores+exp+sum-partials+retrieval-partials, plus per-b LAST BLOCK doing
// the k7 finish. Fence-free cross-block handoff via agent-scope atomics.
__global__ void k45f(const float* __restrict__ memory,
                     const float* __restrict__ Wo, const float* __restrict__ bo,
                     float* ws) {
    __shared__ float esc[64];
    __shared__ float ret[dd];
    __shared__ float sS, sW;
    __shared__ int lflag;
    int blk = blockIdx.x;
    int which = blk >> 9;
    int b = (blk >> 6) & 7;
    int mc = blk & 63;
    int t = threadIdx.x;
    int wave = t >> 6, lane = t & 63;
    const float* tile = ((which == 0) ? memory : memory + (size_t)b*MM*dd)
                        + (size_t)mc*64*dd;
    const f4 qv = ((const f4*)(ws + OFF_Q + b*dd))[lane];
    #pragma unroll 4
    for (int i = 0; i < 16; ++i) {
        int r = i*4 + wave;
        f4 av = ((const f4*)(tile + (size_t)r*dd))[lane];
        f4 pr = av * qv;
        float p = pr.x + pr.y + pr.z + pr.w;
        #pragma unroll
        for (int off = 32; off > 0; off >>= 1) p += __shfl_xor(p, off);
        if (lane == 0) esc[r] = __expf(p);
    }
    __syncthreads();
    if (t < 64) {
        float v = esc[t];
        #pragma unroll
        for (int off = 32; off > 0; off >>= 1) v += __shfl_xor(v, off);
        if (t == 0)
            __hip_atomic_store(ws + OFF_SUMP + which*512 + b*64 + mc, v,
                               __ATOMIC_RELAXED, __HIP_MEMORY_SCOPE_AGENT);
    }
    if (which == 0) {
        float acc = 0.f;
        #pragma unroll 8
        for (int i = 0; i < 64; ++i) acc += esc[i] * tile[(size_t)i*dd + t];
        __hip_atomic_store(ws + OFF_PRET + (size_t)(b*64 + mc)*dd + t, acc,
                           __ATOMIC_RELAXED, __HIP_MEMORY_SCOPE_AGENT);
    } else if (t < 64) {
        ws[OFF_SC + (size_t)b*MM + mc*64 + t] = esc[t];   // plain: read by k8 only
    }
    // ---- last-block election (fence-free) ----
    asm volatile("s_waitcnt vmcnt(0)" ::: "memory");  // own stores at coherent point
    __syncthreads();
    if (t == 0) {
        int prev = __hip_atomic_fetch_add((int*)ws + b, 1,
                                          __ATOMIC_RELAXED, __HIP_MEMORY_SCOPE_AGENT);
        lflag = (prev == 127);
    }
    __syncthreads();
    if (!lflag) return;
    // ---- k7 finish for batch b ----
    float v0 = 0.f, v1 = 0.f;
    if (t < 64) {
        v0 = __hip_atomic_load(ws + OFF_SUMP + b*64 + t,
                               __ATOMIC_RELAXED, __HIP_MEMORY_SCOPE_AGENT);
        v1 = __hip_atomic_load(ws + OFF_SUMP + 512 + b*64 + t,
                               __ATOMIC_RELAXED, __HIP_MEMORY_SCOPE_AGENT);
        #pragma unroll
        for (int off = 32; off > 0; off >>= 1) {
            v0 += __shfl_xor(v0, off);
            v1 += __shfl_xor(v1, off);
        }
        if (t == 0) { sS = v0; sW = v1; }
    }
    __syncthreads();
    if (t == 0) ws[OFF_COMBO + b] = 0.05f * ws[OFF_GATE + b] / sW;
    float acc0 = 0.f;
    #pragma unroll 8
    for (int m2 = 0; m2 < 64; ++m2)
        acc0 += __hip_atomic_load(ws + OFF_PRET + (size_t)(b*64 + m2)*dd + t,
                                  __ATOMIC_RELAXED, __HIP_MEMORY_SCOPE_AGENT);
    ret[t] = acc0 / sS;
    __syncthreads();
    #pragma unroll
    for (int cg = 0; cg < 4; ++cg) {
        int col = cg*256 + t;
        float acc = 0.f;
        #pragma unroll 8
        for (int j = 0; j < dd; ++j)
            acc += ret[j] * Wo[(size_t)j*DD + col];
        ws[OFF_ROUT + (size_t)b*DD + col] = acc + bo[col];   // plain: read by k8
    }
}

// K8: fused elementwise outputs. f4 grid-stride, grid 4096, nt streaming.
__global__ void k8(const float* __restrict__ x, const float* __restrict__ memory,
                   const float* __restrict__ ws, float* __restrict__ out) {
    const int NA = BB*SS*DD/4;       // 4194304
    const int NT = NA + BB*MM*dd/4;  // 6291456
    const f4* x4 = (const f4*)x;
    const f4* m4 = (const f4*)memory;
    const f4* r4 = (const f4*)(ws + OFF_ROUT);
    const f4* w4 = (const f4*)(ws + OFF_WV);
    f4* o4 = (f4*)out;
    int stride = gridDim.x * blockDim.x;
    for (int i = blockIdx.x*blockDim.x + threadIdx.x; i < NT; i += stride) {
        if (i < NA) {
            int b = i >> 19;
            int c = i & 255;
            f4 xv = __builtin_nontemporal_load(&x4[i]);
            f4 o = xv + r4[(b << 8) + c];
            __builtin_nontemporal_store(o, &o4[i]);
        } else {
            int j = i - NA;
            int b = j >> 18;
            int m = (j >> 6) & (MM-1);
            int d4 = j & 63;
            float coeff = ws[OFF_COMBO + b] * ws[OFF_SC + (size_t)b*MM + m];
            f4 wv = w4[(b << 6) + d4];
            f4 mv = __builtin_nontemporal_load(&m4[j]);
            f4 o = 0.95f*mv + coeff*wv;
            __builtin_nontemporal_store(o, &o4[i]);
        }
    }
}

extern "C" void kernel_launch(void* const* d_in, const int* in_sizes, int n_in,
                              void* d_out, int out_size, void* d_ws, size_t ws_size,
                              hipStream_t stream) {
    const float* x      = (const float*)d_in[0];
    const float* memory = (const float*)d_in[1];
    const float* Wq     = (const float*)d_in[2];
    const float* bq     = (const float*)d_in[3];
    const float* Wv     = (const float*)d_in[4];
    const float* bv     = (const float*)d_in[5];
    const float* Wo     = (const float*)d_in[6];
    const float* bo     = (const float*)d_in[7];
    const float* Wg     = (const float*)d_in[8];
    const float* bg     = (const float*)d_in[9];
    float* out = (float*)d_out;
    float* ws  = (float*)d_ws;

    k1<<<BB*NCHK, 256, 0, stream>>>(x, ws);
    k23<<<72, 512, 0, stream>>>(Wq, bq, Wv, bv, Wg, bg, ws);
    k45f<<<1024, 256, 0, stream>>>(memory, Wo, bo, ws);
    k8<<<4096, 256, 0, stream>>>(x, memory, ws, out);
}

// Round 10
// 84.702 us; speedup vs baseline: 2.8950x; 1.6487x over previous
//
#include <hip/hip_runtime.h>
#include <math.h>

#define BB 8
#define SS 2048
#define DD 1024
#define MM 4096
#define dd 256
#define NCHK 128     // 16-row x chunks

typedef float f4 __attribute__((ext_vector_type(4)));

// ---- ws layout (floats) ----
#define OFF_PART  64                              // [b*128+chunk][1024] = 1048576
#define OFF_Q     (OFF_PART + BB*NCHK*DD)         // 2048
#define OFF_WV    (OFF_Q + 2048)                  // 2048
#define OFF_GATE  (OFF_WV + 2048)                 // 8
#define OFF_COMBO (OFF_GATE + 8)                  // 8
#define OFF_SUMP  (OFF_COMBO + 8)                 // 1024: [which*512 + b*64 + mc]
#define OFF_SC    (OFF_SUMP + 1024)               // 32768: exp write-scores [b][m]
#define OFF_PRET  (OFF_SC + 32768)                // 131072: [(b*64+mc)*256 + j]
#define OFF_ROUT  (OFF_PRET + 131072)             // 8192

// K1: x partial column sums. grid = B*NCHK = 1024, block 256, f4/thread.
__global__ void k1(const float* __restrict__ x, float* __restrict__ ws) {
    int blk = blockIdx.x;
    int chunk = blk & 127;
    int b = blk >> 7;
    int t = threadIdx.x;
    const f4* x4 = (const f4*)(x + ((size_t)b*SS + (size_t)chunk*16)*DD);
    f4 a = (f4)(0.f);
    #pragma unroll
    for (int s = 0; s < 16; ++s)
        a += x4[s*256 + t];
    ((f4*)(ws + OFF_PART))[(size_t)blk*256 + t] = a;
}

// K23: fused projections + gate. grid = 72 blocks, block 512.
__global__ void k23(const float* __restrict__ Wq, const float* __restrict__ bq,
                    const float* __restrict__ Wv, const float* __restrict__ bv,
                    const float* __restrict__ Wg, const float* __restrict__ bg,
                    float* __restrict__ ws) {
    __shared__ f4 xsA[256];
    __shared__ f4 xsB[256];
    __shared__ float red[512];
    int blk = blockIdx.x;
    int t = threadIdx.x;
    const f4* p4 = (const f4*)(ws + OFF_PART);
    if (blk < 64) {
        int cs = blk & 3;
        int wb = blk >> 2;
        int b = wb & 7;
        int which = wb >> 3;
        int col4 = t & 255;
        int half = t >> 8;
        f4 a = (f4)(0.f);
        #pragma unroll 8
        for (int c = 0; c < 64; ++c)
            a += p4[(size_t)(b*NCHK + half*64 + c)*256 + col4];
        if (half == 0) xsA[col4] = a; else xsB[col4] = a;
        __syncthreads();
        if (t < 256) xsA[t] = (xsA[t] + xsB[t]) * (1.f/SS);
        __syncthreads();
        const float* xs = (const float*)xsA;
        const float* W = which ? Wv : Wq;
        int kg = t >> 6;
        int c0 = cs*64 + (t & 63);
        float acc = 0.f;
        #pragma unroll 8
        for (int kk = 0; kk < 128; ++kk) {
            int k = kg*128 + kk;
            acc += xs[k] * W[(size_t)k*dd + c0];
        }
        red[t] = acc;
        __syncthreads();
        if (t < 64) {
            int c = cs*64 + t;
            float o = red[t] + red[t+64] + red[t+128] + red[t+192]
                    + red[t+256] + red[t+320] + red[t+384] + red[t+448];
            o += which ? bv[c] : bq[c];
            ws[(which ? OFF_WV : OFF_Q) + b*dd + c] = o;
        }
    } else {
        int b = blk - 64;
        const float* base = ws + OFF_PART + (size_t)(b*NCHK)*DD;
        float wg0 = Wg[t], wg1 = Wg[t + 512];
        float acc = 0.f;
        #pragma unroll 8
        for (int c = 0; c < NCHK; ++c) {
            const float* p = base + (size_t)c*DD;
            acc += p[t]*wg0 + p[t+512]*wg1;
        }
        red[t] = acc; __syncthreads();
        for (int s2 = 256; s2 > 0; s2 >>= 1) {
            if (t < s2) red[t] += red[t + s2];
            __syncthreads();
        }
        if (t == 0)
            ws[OFF_GATE + b] = 1.f / (1.f + __expf(-(red[0]*(1.f/SS) + bg[0])));
    }
}

// K45: scores+exp+rowsum-partials+retrieval-partials, MLP-optimized.
// grid = 1024: which = blk>>9, b = (blk>>6)&7, mc = blk&63 (64 m-rows/block).
// Score phase: 4 threads per row; thread (r,q) covers cols [64q,64q+64) via
// 16 independent f4 loads; 2-shfl reduce; exp on q==0.
__global__ void k45(const float* __restrict__ memory, float* __restrict__ ws) {
    __shared__ float esc[64];
    int blk = blockIdx.x;
    int which = blk >> 9;
    int b = (blk >> 6) & 7;
    int mc = blk & 63;
    int t = threadIdx.x;
    const float* tile = ((which == 0) ? memory : memory + (size_t)b*MM*dd)
                        + (size_t)mc*64*dd;
    int r = t >> 2, q = t & 3;
    const f4* row4 = (const f4*)(tile + (size_t)r*dd) + q*16;
    const f4* qq4  = (const f4*)(ws + OFF_Q + b*dd) + q*16;
    float p = 0.f;
    #pragma unroll
    for (int k = 0; k < 16; ++k) {
        f4 av = row4[k];
        f4 qv = qq4[k];
        f4 pr = av * qv;
        p += pr.x + pr.y + pr.z + pr.w;
    }
    p += __shfl_xor(p, 1);
    p += __shfl_xor(p, 2);
    if (q == 0) esc[r] = __expf(p);
    __syncthreads();
    if (t < 64) {
        float v = esc[t];
        #pragma unroll
        for (int off = 32; off > 0; off >>= 1) v += __shfl_xor(v, off);
        if (t == 0) ws[OFF_SUMP + which*512 + b*64 + mc] = v;
    }
    if (which == 0) {
        float acc = 0.f;
        #pragma unroll 8
        for (int i = 0; i < 64; ++i) acc += esc[i] * tile[(size_t)i*dd + t];
        ws[OFF_PRET + (size_t)(b*64 + mc)*dd + t] = acc;
    } else if (t < 64) {
        ws[OFF_SC + (size_t)b*MM + mc*64 + t] = esc[t];
    }
}

// K7: SUMP reduce + PRET reduce + normalize + Wo matvec + combo. grid = 128, block 256.
__global__ void k7(const float* __restrict__ Wo, const float* __restrict__ bo,
                   float* __restrict__ ws) {
    __shared__ float ret[dd];
    __shared__ float red[256];
    __shared__ float ssum;
    int blk = blockIdx.x;
    int cb = blk & 15;
    int b = blk >> 4;
    int t = threadIdx.x;
    if (t < 64) {
        float v = ws[OFF_SUMP + b*64 + t];
        #pragma unroll
        for (int off = 32; off > 0; off >>= 1) v += __shfl_xor(v, off);
        if (t == 0) ssum = v;
    } else if (t < 128 && cb == 0) {
        float v = ws[OFF_SUMP + 512 + b*64 + (t - 64)];
        #pragma unroll
        for (int off = 32; off > 0; off >>= 1) v += __shfl_xor(v, off);
        if (t == 64) ws[OFF_COMBO + b] = 0.05f * ws[OFF_GATE + b] / v;
    }
    float acc0 = 0.f;
    #pragma unroll 8
    for (int mc = 0; mc < 64; ++mc)
        acc0 += ws[OFF_PRET + (size_t)(b*64 + mc)*dd + t];
    __syncthreads();
    ret[t] = acc0 / ssum;
    __syncthreads();
    int c = t & 63, jr = t >> 6;
    float acc = 0.f;
    #pragma unroll 8
    for (int jj = 0; jj < 64; ++jj) {
        int j = jr*64 + jj;
        acc += ret[j] * Wo[(size_t)j*DD + cb*64 + c];
    }
    red[t] = acc; __syncthreads();
    if (t < 64) {
        ws[OFF_ROUT + (size_t)b*DD + cb*64 + t] =
            red[t] + red[t+64] + red[t+128] + red[t+192] + bo[cb*64 + t];
    }
}

// K8: fused elementwise outputs. f4 grid-stride, grid 4096, nt stores only.
__global__ void k8(const float* __restrict__ x, const float* __restrict__ memory,
                   const float* __restrict__ ws, float* __restrict__ out) {
    const int NA = BB*SS*DD/4;       // 4194304
    const int NT = NA + BB*MM*dd/4;  // 6291456
    const f4* x4 = (const f4*)x;
    const f4* m4 = (const f4*)memory;
    const f4* r4 = (const f4*)(ws + OFF_ROUT);
    const f4* w4 = (const f4*)(ws + OFF_WV);
    f4* o4 = (f4*)out;
    int stride = gridDim.x * blockDim.x;
    for (int i = blockIdx.x*blockDim.x + threadIdx.x; i < NT; i += stride) {
        if (i < NA) {
            int b = i >> 19;
            int c = i & 255;
            f4 o = x4[i] + r4[(b << 8) + c];
            __builtin_nontemporal_store(o, &o4[i]);
        } else {
            int j = i - NA;
            int b = j >> 18;
            int m = (j >> 6) & (MM-1);
            int d4 = j & 63;
            float coeff = ws[OFF_COMBO + b] * ws[OFF_SC + (size_t)b*MM + m];
            f4 o = 0.95f*m4[j] + coeff*w4[(b << 6) + d4];
            __builtin_nontemporal_store(o, &o4[i]);
        }
    }
}

extern "C" void kernel_launch(void* const* d_in, const int* in_sizes, int n_in,
                              void* d_out, int out_size, void* d_ws, size_t ws_size,
                              hipStream_t stream) {
    const float* x      = (const float*)d_in[0];
    const float* memory = (const float*)d_in[1];
    const float* Wq     = (const float*)d_in[2];
    const float* bq     = (const float*)d_in[3];
    const float* Wv     = (const float*)d_in[4];
    const float* bv     = (const float*)d_in[5];
    const float* Wo     = (const float*)d_in[6];
    const float* bo     = (const float*)d_in[7];
    const float* Wg     = (const float*)d_in[8];
    const float* bg     = (const float*)d_in[9];
    float* out = (float*)d_out;
    float* ws  = (float*)d_ws;

    k1<<<BB*NCHK, 256, 0, stream>>>(x, ws);
    k23<<<72, 512, 0, stream>>>(Wq, bq, Wv, bv, Wg, bg, ws);
    k45<<<1024, 256, 0, stream>>>(memory, ws);
    k7<<<BB*16, 256, 0, stream>>>(Wo, bo, ws);
    k8<<<4096, 256, 0, stream>>>(x, memory, ws, out);
}

// Round 11
// 74.122 us; speedup vs baseline: 3.3082x; 1.1427x over previous
//
#include <hip/hip_runtime.h>
#include <math.h>

#define BB 8
#define SS 2048
#define DD 1024
#define MM 4096
#define dd 256
#define NCH 64          // S-chunks for x column-sum
#define CS (SS/NCH)     // 32 rows per chunk

typedef float f4 __attribute__((ext_vector_type(4)));

// ---- ws layout (floats) ----
#define OFF_PART  0                        // [b*64+chunk][1024] = 524288
#define OFF_Q     524288                   // 2048
#define OFF_WV    526336                   // 2048
#define OFF_GATE  528384                   // 8
#define OFF_COMBO 528392                   // 8
#define OFF_SUMP  528400                   // 2048: [which*1024 + b*128 + mc]
#define OFF_SC    530448                   // 32768: exp write-scores [b][m]
#define OFF_PRET  563216                   // 262144: [(b*128+mc)*256 + j]
#define OFF_ROUT  825360                   // 8192

// K1: x partial column sums. grid = B*NCH = 512, block 256, f4/thread. (R6 proven)
__global__ void k1(const float* __restrict__ x, float* __restrict__ ws) {
    int blk = blockIdx.x;
    int chunk = blk & 63;
    int b = blk >> 6;
    int t = threadIdx.x;
    const f4* x4 = (const f4*)(x + ((size_t)b*SS + (size_t)chunk*CS)*DD);
    f4 a = (f4)(0.f);
    #pragma unroll 8
    for (int s = 0; s < CS; ++s) a += x4[s*256 + t];
    ((f4*)(ws + OFF_PART))[(size_t)blk*256 + t] = a;
}

// K23: fused projections + gate. grid = 72 blocks, block 512. (R6 proven)
__global__ void k23(const float* __restrict__ Wq, const float* __restrict__ bq,
                    const float* __restrict__ Wv, const float* __restrict__ bv,
                    const float* __restrict__ Wg, const float* __restrict__ bg,
                    float* __restrict__ ws) {
    __shared__ f4 xsA[256];
    __shared__ f4 xsB[256];
    __shared__ float red[512];
    int blk = blockIdx.x;
    int t = threadIdx.x;
    const f4* p4 = (const f4*)(ws + OFF_PART);
    if (blk < 64) {
        int cs = blk & 3;
        int wb = blk >> 2;
        int b = wb & 7;
        int which = wb >> 3;
        int col4 = t & 255;
        int half = t >> 8;
        f4 a = (f4)(0.f);
        #pragma unroll 8
        for (int c = 0; c < 32; ++c)
            a += p4[(size_t)(b*NCH + half*32 + c)*256 + col4];
        if (half == 0) xsA[col4] = a; else xsB[col4] = a;
        __syncthreads();
        if (t < 256) xsA[t] = (xsA[t] + xsB[t]) * (1.f/SS);
        __syncthreads();
        const float* xs = (const float*)xsA;
        const float* W = which ? Wv : Wq;
        int kg = t >> 6;
        int c0 = cs*64 + (t & 63);
        float acc = 0.f;
        #pragma unroll 8
        for (int kk = 0; kk < 128; ++kk) {
            int k = kg*128 + kk;
            acc += xs[k] * W[(size_t)k*dd + c0];
        }
        red[t] = acc;
        __syncthreads();
        if (t < 64) {
            int c = cs*64 + t;
            float o = red[t] + red[t+64] + red[t+128] + red[t+192]
                    + red[t+256] + red[t+320] + red[t+384] + red[t+448];
            o += which ? bv[c] : bq[c];
            ws[(which ? OFF_WV : OFF_Q) + b*dd + c] = o;
        }
    } else {
        int b = blk - 64;
        const float* base = ws + OFF_PART + (size_t)(b*NCH)*DD;
        float wg0 = Wg[t], wg1 = Wg[t + 512];
        float acc = 0.f;
        #pragma unroll 8
        for (int c = 0; c < NCH; ++c) {
            const float* p = base + (size_t)c*DD;
            acc += p[t]*wg0 + p[t+512]*wg1;
        }
        red[t] = acc; __syncthreads();
        for (int s2 = 256; s2 > 0; s2 >>= 1) {
            if (t < s2) red[t] += red[t + s2];
            __syncthreads();
        }
        if (t == 0)
            ws[OFF_GATE + b] = 1.f / (1.f + __expf(-(red[0]*(1.f/SS) + bg[0])));
    }
}

// K45: scores+exp+rowsum-partials+retrieval-partials. 32-row chunks.
// grid = 2048: which = blk>>10, b = (blk>>7)&7, mc = blk&127. Full occupancy.
__global__ __launch_bounds__(256, 8)
void k45(const float* __restrict__ memory, float* __restrict__ ws) {
    __shared__ float esc[32];
    int blk = blockIdx.x;
    int which = blk >> 10;
    int b = (blk >> 7) & 7;
    int mc = blk & 127;
    int t = threadIdx.x;
    int wave = t >> 6, lane = t & 63;
    const float* tile = ((which == 0) ? memory : memory + (size_t)b*MM*dd)
                        + (size_t)mc*32*dd;
    const f4 qv = ((const f4*)(ws + OFF_Q + b*dd))[lane];
    // wave-per-row coalesced scores: 8 serial rows per wave
    #pragma unroll
    for (int i = 0; i < 8; ++i) {
        int r = i*4 + wave;
        f4 av = ((const f4*)(tile + (size_t)r*dd))[lane];
        f4 pr = av * qv;
        float p = pr.x + pr.y + pr.z + pr.w;
        #pragma unroll
        for (int off = 32; off > 0; off >>= 1) p += __shfl_xor(p, off);
        if (lane == 0) esc[r] = __expf(p);
    }
    __syncthreads();
    if (t < 32) {
        float v = esc[t];
        #pragma unroll
        for (int off = 16; off > 0; off >>= 1) v += __shfl_xor(v, off);
        if (t == 0) ws[OFF_SUMP + which*1024 + b*128 + mc] = v;
    }
    if (which == 0) {
        float acc = 0.f;
        #pragma unroll 8
        for (int i = 0; i < 32; ++i) acc += esc[i] * tile[(size_t)i*dd + t];
        ws[OFF_PRET + (size_t)(b*128 + mc)*dd + t] = acc;
    } else if (t < 32) {
        ws[OFF_SC + (size_t)b*MM + mc*32 + t] = esc[t];
    }
}

// K7: SUMP reduce + PRET reduce + normalize + Wo matvec + combo. grid = 128.
__global__ void k7(const float* __restrict__ Wo, const float* __restrict__ bo,
                   float* __restrict__ ws) {
    __shared__ float ret[dd];
    __shared__ float red[256];
    __shared__ float ssum;
    int blk = blockIdx.x;
    int cb = blk & 15;
    int b = blk >> 4;
    int t = threadIdx.x;
    if (t < 64) {
        float v = ws[OFF_SUMP + b*128 + t] + ws[OFF_SUMP + b*128 + 64 + t];
        #pragma unroll
        for (int off = 32; off > 0; off >>= 1) v += __shfl_xor(v, off);
        if (t == 0) ssum = v;
    } else if (t < 128 && cb == 0) {
        int u = t - 64;
        float v = ws[OFF_SUMP + 1024 + b*128 + u] + ws[OFF_SUMP + 1024 + b*128 + 64 + u];
        #pragma unroll
        for (int off = 32; off > 0; off >>= 1) v += __shfl_xor(v, off);
        if (t == 64) ws[OFF_COMBO + b] = 0.05f * ws[OFF_GATE + b] / v;
    }
    float acc0 = 0.f;
    #pragma unroll 8
    for (int mc = 0; mc < 128; ++mc)
        acc0 += ws[OFF_PRET + (size_t)(b*128 + mc)*dd + t];
    __syncthreads();
    ret[t] = acc0 / ssum;
    __syncthreads();
    int c = t & 63, jr = t >> 6;
    float acc = 0.f;
    #pragma unroll 8
    for (int jj = 0; jj < 64; ++jj) {
        int j = jr*64 + jj;
        acc += ret[j] * Wo[(size_t)j*DD + cb*64 + c];
    }
    red[t] = acc; __syncthreads();
    if (t < 64) {
        ws[OFF_ROUT + (size_t)b*DD + cb*64 + t] =
            red[t] + red[t+64] + red[t+128] + red[t+192] + bo[cb*64 + t];
    }
}

// K8: fused elementwise outputs. f4 grid-stride, grid 4096, nt stores.
__global__ void k8(const float* __restrict__ x, const float* __restrict__ memory,
                   const float* __restrict__ ws, float* __restrict__ out) {
    const int NA = BB*SS*DD/4;       // 4194304
    const int NT = NA + BB*MM*dd/4;  // 6291456
    const f4* x4 = (const f4*)x;
    const f4* m4 = (const f4*)memory;
    const f4* r4 = (const f4*)(ws + OFF_ROUT);
    const f4* w4 = (const f4*)(ws + OFF_WV);
    f4* o4 = (f4*)out;
    int stride = gridDim.x * blockDim.x;
    for (int i = blockIdx.x*blockDim.x + threadIdx.x; i < NT; i += stride) {
        if (i < NA) {
            int b = i >> 19;
            int c = i & 255;
            f4 o = x4[i] + r4[(b << 8) + c];
            __builtin_nontemporal_store(o, &o4[i]);
        } else {
            int j = i - NA;
            int b = j >> 18;
            int m = (j >> 6) & (MM-1);
            int d4 = j & 63;
            float coeff = ws[OFF_COMBO + b] * ws[OFF_SC + (size_t)b*MM + m];
            f4 o = 0.95f*m4[j] + coeff*w4[(b << 6) + d4];
            __builtin_nontemporal_store(o, &o4[i]);
        }
    }
}

extern "C" void kernel_launch(void* const* d_in, const int* in_sizes, int n_in,
                              void* d_out, int out_size, void* d_ws, size_t ws_size,
                              hipStream_t stream) {
    const float* x      = (const float*)d_in[0];
    const float* memory = (const float*)d_in[1];
    const float* Wq     = (const float*)d_in[2];
    const float* bq     = (const float*)d_in[3];
    const float* Wv     = (const float*)d_in[4];
    const float* bv     = (const float*)d_in[5];
    const float* Wo     = (const float*)d_in[6];
    const float* bo     = (const float*)d_in[7];
    const float* Wg     = (const float*)d_in[8];
    const float* bg     = (const float*)d_in[9];
    float* out = (float*)d_out;
    float* ws  = (float*)d_ws;

    k1<<<BB*NCH, 256, 0, stream>>>(x, ws);
    k23<<<72, 512, 0, stream>>>(Wq, bq, Wv, bv, Wg, bg, ws);
    k45<<<2048, 256, 0, stream>>>(memory, ws);
    k7<<<BB*16, 256, 0, stream>>>(Wo, bo, ws);
    k8<<<4096, 256, 0, stream>>>(x, memory, ws, out);
}